// Round 12
// baseline (65083.630 us; speedup 1.0000x reference)
//
#include <hip/hip_runtime.h>

// ======================= ws layout (bytes) =======================
static constexpr size_t OFF_ENC   = 0;          // bf16 [128 b][256 l][1024 f] = 64 MiB
// ---- enc-phase overlay (round-3/7 proven packing) ----
static constexpr size_t OFF_WGE   = 67108864;   // WHHE [2dir][256 k2][512 j][8] (4 MiB) + WIHT (1 MiB)
static constexpr size_t OFF_HENC  = 72351744;   // bf16 paired [(dir*2+par)][256 kk][128 b]
static constexpr size_t OFF_CENC  = 72876032;   // f32  [2dir][512][128]
// ---- dec-phase overlay (written by pre2p AFTER k_h0) ----
static constexpr size_t OFF_WGP   = 67108864;   // uint4 [k8 128][row 2048]  (4 MiB)   gates
static constexpr size_t OFF_XDEC  = 71303168;   // bf16 [v 128][row 2048]    (512 KiB) x-embed
static constexpr size_t OFF_WATTP = 71827456;   // uint4 [o8 64][i 1024]     (1 MiB)   u
static constexpr size_t OFF_WOUTP = 72876032;   // uint4 [k8 192][n 512]     (1.5 MiB) wout
static constexpr size_t OFF_WVOCP = 74448896;   // uint4 [k8 64][v 128]      (128 KiB) vocab
// ---- handoff state (enc->dec) ----
static constexpr size_t OFF_HDEC  = 74579968;   // bf16 paired [256 kk][128 b]  (h0)
static constexpr size_t OFF_CDEC  = 74842112;   // f32 [512][128]               (c0)

// ======================= helpers =======================
__device__ __forceinline__ float sigm(float x) { return 1.f / (1.f + expf(-x)); }
__device__ __forceinline__ unsigned short f2bf(float f) {
  unsigned u = __float_as_uint(f);
  u += 0x7fffu + ((u >> 16) & 1u);
  return (unsigned short)(u >> 16);
}
__device__ __forceinline__ float bfl(unsigned w) { return __uint_as_float(w << 16); }
__device__ __forceinline__ float bfh(unsigned w) { return __uint_as_float(w & 0xffff0000u); }
__device__ __forceinline__ float bf2f(unsigned short v) { return __uint_as_float(((unsigned)v) << 16); }
__device__ __forceinline__ unsigned packbf(float lo, float hi) {
  return (unsigned)f2bf(lo) | ((unsigned)f2bf(hi) << 16);
}

#if defined(__has_builtin)
#if __has_builtin(__builtin_amdgcn_fdot2_f32_bf16)
#define HAVE_DOT2BF 1
#endif
#endif
#ifdef HAVE_DOT2BF
typedef __bf16 bf2_t __attribute__((ext_vector_type(2)));
__device__ __forceinline__ float dot2bf(unsigned w, unsigned h, float acc) {
  return __builtin_amdgcn_fdot2_f32_bf16(__builtin_bit_cast(bf2_t, w),
                                         __builtin_bit_cast(bf2_t, h), acc, false);
}
#else
__device__ __forceinline__ float dot2bf(unsigned w, unsigned h, float acc) {
  return acc + bfl(w) * bfl(h) + bfh(w) * bfh(h);
}
#endif
__device__ __forceinline__ float dot4q(uint4 W, uint4 I, float a) {
  a = dot2bf(W.x, I.x, a); a = dot2bf(W.y, I.y, a);
  a = dot2bf(W.z, I.z, a); a = dot2bf(W.w, I.w, a);
  return a;
}

// ======================= pre1: encoder weight packing (proven) ==============
__global__ __launch_bounds__(256) void k_pre1(const float* __restrict__ WhhF,
                                              const float* __restrict__ WhhB,
                                              const float* __restrict__ WihF,
                                              const float* __restrict__ WihB,
                                              char* __restrict__ wsb) {
  unsigned short* dst = (unsigned short*)(wsb + OFF_WGE);
  int id = blockIdx.x * 256 + threadIdx.x, str = gridDim.x * 256;
  for (int x = id; x < 2097152; x += str) {           // WHHE [dir][k2][j][8], e=g*2+kk
    int dir = x >> 20, r = x & 1048575;
    int e = r & 7, j = (r >> 3) & 511, k2 = r >> 12;
    int g = e >> 1, k = k2 * 2 + (e & 1);
    const float* W = dir ? WhhB : WhhF;
    dst[x] = f2bf(W[((size_t)g * 512 + j) * 512 + k]);
  }
  for (int x = id; x < 524288; x += str) {            // WIHT [dir][v][j][4]
    int dir = x >> 18, r = x & 262143;
    int g = r & 3, j = (r >> 2) & 511, v = r >> 11;
    const float* W = dir ? WihB : WihF;
    dst[2097152 + x] = f2bf(W[((size_t)g * 512 + j) * 128 + v]);
  }
}

// ======================= encoder: one block per (b, dir) (proven) ====
__global__ __launch_bounds__(512) void k_enc(const float* __restrict__ bF,
                                             const float* __restrict__ bB,
                                             const int* __restrict__ C_idx,
                                             char* __restrict__ wsb) {
  __shared__ __align__(16) unsigned short hbf[512];
  int bid = blockIdx.x;
  int b = bid & 127, dir = bid >> 7;
  int j = threadIdx.x;
  const unsigned short* WH = (const unsigned short*)(wsb + OFF_WGE) + (size_t)dir * 1048576;
  const unsigned short* WX = (const unsigned short*)(wsb + OFF_WGE) + 2097152 + (size_t)dir * 262144;
  const float* bias = dir ? bB : bF;
  float b0 = bias[j], b1 = bias[512 + j], b2 = bias[1024 + j], b3 = bias[1536 + j];
  unsigned short* encb = (unsigned short*)wsb + (size_t)b * 262144;
  const uint4* wp = (const uint4*)WH + j;
  float c = 0.f, h = 0.f;
  hbf[j] = 0;
  __syncthreads();
  for (int t = 0; t < 256; ++t) {
    int l = dir ? (255 - t) : t;
    int cidx = C_idx[b * 256 + l];
    uint2 xg = *(const uint2*)(WX + ((size_t)cidx * 512 + j) * 4);
    float a0 = b0 + bfl(xg.x), a1 = b1 + bfh(xg.x);
    float a2 = b2 + bfl(xg.y), a3 = b3 + bfh(xg.y);
    for (int k2 = 0; k2 < 256; ++k2) {
      uint4 w = wp[(size_t)k2 * 512];
      unsigned hp = *(const unsigned*)((const char*)hbf + k2 * 4);
      a0 = dot2bf(w.x, hp, a0);
      a1 = dot2bf(w.y, hp, a1);
      a2 = dot2bf(w.z, hp, a2);
      a3 = dot2bf(w.w, hp, a3);
    }
    float ig = sigm(a0), fg = sigm(a1), gg = tanhf(a2), og = sigm(a3);
    c = fg * c + ig * gg;
    h = og * tanhf(c);
    __syncthreads();
    unsigned short hb = f2bf(h);
    hbf[j] = hb;
    encb[(size_t)l * 1024 + dir * 512 + j] = hb;
    __syncthreads();
  }
  ((unsigned short*)(wsb + OFF_HENC))[(((size_t)(dir * 2 + 0) * 256 + (j >> 1)) * 128 + b) * 2 + (j & 1)] = f2bf(h);
  ((float*)(wsb + OFF_CENC))[((size_t)dir * 512 + j) * 128 + b] = c;
}

// ======================= h0/c0 (proven) =======================
__global__ __launch_bounds__(512) void k_h0(const float* __restrict__ Wh,
                                            const float* __restrict__ Wc,
                                            char* __restrict__ wsb) {
  int tau = threadIdx.x;
  int b = tau & 127, slot = tau >> 7;
  int row = __builtin_amdgcn_readfirstlane(blockIdx.x * 4 + slot);
  int sel = row >> 9, j = row & 511;
  const float* W = (sel ? Wc : Wh) + (size_t)j * 1024;
  const unsigned short* HE = (const unsigned short*)(wsb + OFF_HENC);
  const float* CE = (const float*)(wsb + OFF_CENC);
  float acc = 0.f;
  for (int k = 0; k < 1024; ++k) {
    int dir = k >> 9, k5 = k & 511;
    float in;
    if (sel == 0)
      in = bf2f(HE[(((size_t)(dir * 2 + 0) * 256 + (k5 >> 1)) * 128 + b) * 2 + (k5 & 1)]);
    else
      in = CE[((size_t)dir * 512 + k5) * 128 + b];
    acc += W[k] * in;
  }
  if (sel == 0)
    ((unsigned short*)(wsb + OFF_HDEC))[(((size_t)(j >> 1)) * 128 + b) * 2 + (j & 1)] = f2bf(acc);
  else
    ((float*)(wsb + OFF_CDEC))[(size_t)j * 128 + b] = acc;
}

// ======================= pre2p: decoder weights, k-major packed ==================
__global__ __launch_bounds__(256) void k_pre2p(const float* __restrict__ dWih,
                                               const float* __restrict__ dWhh,
                                               const float* __restrict__ Wattn,
                                               const float* __restrict__ Wout,
                                               const float* __restrict__ Wvoc,
                                               char* __restrict__ wsb) {
  unsigned* WG = (unsigned*)(wsb + OFF_WGP);
  unsigned short* XD = (unsigned short*)(wsb + OFF_XDEC);
  unsigned* WA = (unsigned*)(wsb + OFF_WATTP);
  unsigned* WO = (unsigned*)(wsb + OFF_WOUTP);
  unsigned* WV = (unsigned*)(wsb + OFF_WVOCP);
  int id = blockIdx.x * 256 + threadIdx.x, str = gridDim.x * 256;
  // WGP: uint4[k8][r] -> u32 x = k8*8192 + r*4 + j ; input dim d over [prev_out(512); h(512)]
  for (int x = id; x < 1048576; x += str) {
    int j = x & 3, r = (x >> 2) & 2047, k8 = x >> 13;
    int d0 = k8 * 8 + 2 * j;
    float v0 = (d0 < 512) ? dWih[(size_t)r * 640 + 128 + d0] : dWhh[(size_t)r * 512 + (d0 - 512)];
    int d1 = d0 + 1;
    float v1 = (d1 < 512) ? dWih[(size_t)r * 640 + 128 + d1] : dWhh[(size_t)r * 512 + (d1 - 512)];
    WG[x] = packbf(v0, v1);
  }
  // XDEC [v][row]
  for (int x = id; x < 128 * 2048; x += str) {
    int v = x >> 11, r = x & 2047;
    XD[x] = f2bf(dWih[(size_t)r * 640 + v]);
  }
  // WATTP: u32 x = o8*4096 + i*4 + j ; u[i] = sum_o Wattn[o][i] h[o]
  for (int x = id; x < 262144; x += str) {
    int j = x & 3, i = (x >> 2) & 1023, o8 = x >> 12;
    int o0 = o8 * 8 + 2 * j;
    WA[x] = packbf(Wattn[(size_t)o0 * 1024 + i], Wattn[(size_t)(o0 + 1) * 1024 + i]);
  }
  // WOUTP: u32 x = k8*2048 + n*4 + j ; d over [h(512); ctx(1024)]
  for (int x = id; x < 393216; x += str) {
    int j = x & 3, n = (x >> 2) & 511, k8 = x >> 11;
    int d0 = k8 * 8 + 2 * j;
    WO[x] = packbf(Wout[(size_t)n * 1536 + d0], Wout[(size_t)n * 1536 + d0 + 1]);
  }
  // WVOCP: u32 x = k8*512 + v*4 + j
  for (int x = id; x < 32768; x += str) {
    int j = x & 3, v = (x >> 2) & 127, k8 = x >> 9;
    int d0 = k8 * 8 + 2 * j;
    WV[x] = packbf(Wvoc[(size_t)v * 512 + d0], Wvoc[(size_t)v * 512 + d0 + 1]);
  }
}

// ======================= THE decoder: one block per b, all 256 steps ==================
__global__ __launch_bounds__(512) void k_dec(const int* __restrict__ C_idx,
                                             const int* __restrict__ E_idx,
                                             const unsigned char* __restrict__ C_pad,
                                             const float* __restrict__ db,
                                             const float* __restrict__ pgc,
                                             const float* __restrict__ pgi,
                                             const float* __restrict__ pgh,
                                             const float* __restrict__ pgcc,
                                             const float* __restrict__ pgb,
                                             char* __restrict__ wsb,
                                             float* __restrict__ out) {
  __shared__ __align__(16) unsigned short tile[32 * 1024];  // 64 KiB enc staging
  __shared__ __align__(16) unsigned in8[512];   // [0..255] prev_out pairs, [256..511] h pairs
  __shared__ __align__(16) unsigned ulds[512];  // u pairs
  __shared__ __align__(16) unsigned ctxp[512];  // ctx pairs
  __shared__ float scf[256];
  __shared__ float sc_l[32];
  __shared__ float p_l[32];
  __shared__ float red[16];
  __shared__ float lgp[4][128];
  __shared__ float lgf[128];
  __shared__ float mdl[4];
  __shared__ int eix[257];
  __shared__ int ci[256];
  __shared__ unsigned char cpad[256];

  int b = blockIdx.x, tau = threadIdx.x;
  int lane = tau & 63, wv = tau >> 6;

  const uint4* WG4 = (const uint4*)(wsb + OFF_WGP);
  const unsigned short* XD = (const unsigned short*)(wsb + OFF_XDEC);
  const uint4* WA4 = (const uint4*)(wsb + OFF_WATTP);
  const uint4* WO4 = (const uint4*)(wsb + OFF_WOUTP);
  const uint4* WV4 = (const uint4*)(wsb + OFF_WVOCP);
  const unsigned short* encB = (const unsigned short*)wsb + (size_t)b * 262144;

  // ---- prologue ----
  if (tau < 256) {
    ci[tau] = C_idx[b * 256 + tau];
    cpad[tau] = C_pad[b * 256 + tau];
    in8[tau] = 0;                                                          // prev_out = 0
    in8[256 + tau] = ((const unsigned*)(wsb + OFF_HDEC))[(size_t)tau * 128 + b];  // h0
  }
  if (tau < 257) eix[tau] = E_idx[b * 257 + tau];
  float c = ((const float*)(wsb + OFF_CDEC))[(size_t)tau * 128 + b];       // c0 (one-time uncoalesced)
  float db0 = db[tau], db1 = db[512 + tau], db2 = db[1024 + tau], db3 = db[1536 + tau];
  float pgc0 = pgc[2 * tau], pgc1 = pgc[2 * tau + 1];
  float pghr = pgh[tau], pgcr = pgcc[tau], pgir = pgi[128 + tau];
  float pgb0 = pgb[0];
  __syncthreads();

  const uint4* in4 = (const uint4*)in8;
  const uint4* ctx4 = (const uint4*)ctxp;
  const uint4* u4 = (const uint4*)ulds;
  const uint4* t4 = (const uint4*)tile;
  const unsigned* tl = (const unsigned*)tile;

  for (int t = 0; t < 256; ++t) {
    int xid = eix[t], tgt = eix[t + 1];
    // ======== gates ========
    const unsigned short* xg = XD + (size_t)xid * 2048;
    float a0 = db0 + bf2f(xg[tau]);
    float a1 = db1 + bf2f(xg[512 + tau]);
    float a2 = db2 + bf2f(xg[1024 + tau]);
    float a3 = db3 + bf2f(xg[1536 + tau]);
#pragma unroll 2
    for (int k8 = 0; k8 < 128; ++k8) {
      uint4 iv = in4[k8];
      const uint4* wp = WG4 + (size_t)k8 * 2048;
      a0 = dot4q(wp[tau], iv, a0);
      a1 = dot4q(wp[512 + tau], iv, a1);
      a2 = dot4q(wp[1024 + tau], iv, a2);
      a3 = dot4q(wp[1536 + tau], iv, a3);
    }
    float ig = sigm(a0), fg = sigm(a1), gg = tanhf(a2), og = sigm(a3);
    c = fg * c + ig * gg;
    float h = og * tanhf(c);
    __syncthreads();                         // all in8 reads done
    ((unsigned short*)in8)[512 + tau] = f2bf(h);   // h slot <- h(t)
    __syncthreads();
    // ======== u ========
    float ua = 0.f, ub = 0.f;
#pragma unroll 4
    for (int o8 = 0; o8 < 64; ++o8) {
      uint4 hv = in4[64 + o8];
      const uint4* wp = WA4 + (size_t)o8 * 1024;
      ua = dot4q(wp[tau], hv, ua);
      ub = dot4q(wp[512 + tau], hv, ub);
    }
    ((unsigned short*)ulds)[tau] = f2bf(ua);
    ((unsigned short*)ulds)[512 + tau] = f2bf(ub);
    // ======== attn (flash, 8 x 32-row tiles; attn1b proven body) ========
    float mold = -3.0e38f, ssum = 0.f, acc0 = 0.f, acc1 = 0.f;
    for (int sub = 0; sub < 8; ++sub) {
      const uint4* src = (const uint4*)encB + (size_t)sub * 4096;
      __syncthreads();                       // tile/ulds safe to (re)use
#pragma unroll
      for (int it = 0; it < 8; ++it) ((uint4*)tile)[it * 512 + tau] = src[it * 512 + tau];
      __syncthreads();
      uint4 uaV = u4[lane * 2], ubV = u4[lane * 2 + 1];
#pragma unroll
      for (int li = 0; li < 4; ++li) {
        int l = wv * 4 + li;
        uint4 ea = t4[l * 128 + lane * 2];
        uint4 eb = t4[l * 128 + lane * 2 + 1];
        float s = 0.f;
        s = dot4q(ea, uaV, s);
        s = dot4q(eb, ubV, s);
        for (int o = 32; o; o >>= 1) s += __shfl_xor(s, o);
        if (lane == 0) {
          int gl = sub * 32 + l;
          if (cpad[gl]) s = -3.0e38f;
          sc_l[l] = s;
          scf[gl] = s;
        }
      }
      __syncthreads();
      if (tau < 64) {
        float v = (tau < 32) ? sc_l[tau] : -3.0e38f;
        for (int o = 32; o; o >>= 1) v = fmaxf(v, __shfl_xor(v, o));
        if (tau == 0) red[0] = v;
      }
      __syncthreads();
      float mnew = fmaxf(mold, red[0]);
      float r = expf(mold - mnew);
      if (tau < 64) {
        float pv = (tau < 32) ? expf(sc_l[tau] - mnew) : 0.f;
        if (tau < 32) p_l[tau] = pv;
        for (int o = 32; o; o >>= 1) pv += __shfl_xor(pv, o);
        if (tau == 0) red[1] = pv;
      }
      __syncthreads();
      ssum = ssum * r + red[1];
      mold = mnew;
      acc0 *= r; acc1 *= r;
#pragma unroll 8
      for (int l = 0; l < 32; ++l) {
        float pv = p_l[l];
        unsigned ev = tl[l * 512 + tau];
        acc0 += pv * bfl(ev); acc1 += pv * bfh(ev);
      }
    }
    float invD = 1.f / ssum;
    float x0 = acc0 * invD, x1 = acc1 * invD;
    ctxp[tau] = packbf(x0, x1);
    // ---- pgen (proven section; reads OLD prev slot) ----
    float pp = x0 * pgc0 + x1 * pgc1;
    {
      unsigned hw = in8[256 + (tau >> 1)];
      float hv = (tau & 1) ? bfh(hw) : bfl(hw);
      unsigned tw = in8[tau >> 1];
      float tv = (tau & 1) ? bfh(tw) : bfl(tw);
      pp += hv * pghr + c * pgcr + tv * pgir;
    }
    for (int o = 32; o; o >>= 1) pp += __shfl_xor(pp, o);
    if (lane == 0) red[8 + wv] = pp;
    __syncthreads();                         // ctxp visible; pgen prev-reads done
    if (tau == 0) {
      float s = red[8] + red[9] + red[10] + red[11] + red[12] + red[13] + red[14] + red[15];
      s += pgi[xid] + pgb0;
      mdl[0] = sigm(s);
    }
    // ======== wout ========
    float aw = 0.f;
#pragma unroll 2
    for (int k8 = 0; k8 < 192; ++k8) {
      uint4 iv = (k8 < 64) ? in4[64 + k8] : ctx4[k8 - 64];
      aw = dot4q((WO4 + (size_t)k8 * 512)[tau], iv, aw);
    }
    float tv2 = tanhf(aw);
    __syncthreads();                         // everyone past pgen prev-reads
    ((unsigned short*)in8)[tau] = f2bf(tv2); // prev slot <- t_out(t)
    __syncthreads();
    // ======== fin: vocab softmax at tgt + copy mass + nll ========
    {
      int v = tau & 127, seg = tau >> 7;
      float af = 0.f;
#pragma unroll
      for (int q = 0; q < 16; ++q) {
        int k8 = seg * 16 + q;
        af = dot4q((WV4 + (size_t)k8 * 128)[v], in4[k8], af);
      }
      lgp[seg][v] = af;
    }
    __syncthreads();
    if (tau < 128) {
      float lg = lgp[0][tau] + lgp[1][tau] + lgp[2][tau] + lgp[3][tau];
      lgf[tau] = lg;
      float m = lg;
      for (int o = 32; o; o >>= 1) m = fmaxf(m, __shfl_xor(m, o));
      if (lane == 0) red[wv] = m;
    }
    __syncthreads();
    float mx = fmaxf(red[0], red[1]);
    if (tau < 128) {
      float e = expf(lgf[tau] - mx);
      for (int o = 32; o; o >>= 1) e += __shfl_xor(e, o);
      if (lane == 0) red[2 + wv] = e;
    }
    float cm = 0.f;
    if (tau < 256) {
      if (ci[tau] == tgt) cm = expf(scf[tau] - mold);
    }
    for (int o = 32; o; o >>= 1) cm += __shfl_xor(cm, o);
    if (lane == 0 && wv < 4) red[4 + wv] = cm;
    __syncthreads();
    if (tau == 0) {
      float sume = red[2] + red[3];
      float copy_raw = (red[4] + red[5] + red[6] + red[7]) / ssum;
      float gen_tgt = expf(lgf[tgt] - mx) / sume;
      float pg = mdl[0];
      float prob = pg * gen_tgt + (1.f - pg) * copy_raw;
      out[b * 256 + t] = (tgt == 0) ? 0.f : -logf(prob);
    }
    __syncthreads();                         // scf/lgp/red safe for next step
  }
}

// ======================= host =======================
extern "C" void kernel_launch(void* const* d_in, const int* in_sizes, int n_in,
                              void* d_out, int out_size, void* d_ws, size_t ws_size,
                              hipStream_t stream) {
  (void)in_sizes; (void)n_in; (void)out_size; (void)ws_size;
  const int* C_idx = (const int*)d_in[0];
  const int* E_idx = (const int*)d_in[1];
  const unsigned char* C_pad = (const unsigned char*)d_in[2];
  const float* eWihF = (const float*)d_in[3];
  const float* eWhhF = (const float*)d_in[4];
  const float* ebF   = (const float*)d_in[5];
  const float* eWihB = (const float*)d_in[6];
  const float* eWhhB = (const float*)d_in[7];
  const float* ebB   = (const float*)d_in[8];
  const float* dWih  = (const float*)d_in[9];
  const float* dWhh  = (const float*)d_in[10];
  const float* db    = (const float*)d_in[11];
  const float* Wh    = (const float*)d_in[12];
  const float* Wc    = (const float*)d_in[13];
  const float* Wattn = (const float*)d_in[14];
  const float* Wout  = (const float*)d_in[15];
  const float* Wvoc  = (const float*)d_in[16];
  const float* pgc   = (const float*)d_in[17];
  const float* pgi   = (const float*)d_in[18];
  const float* pgh   = (const float*)d_in[19];
  const float* pgcc  = (const float*)d_in[20];
  const float* pgb   = (const float*)d_in[21];
  char* wsb = (char*)d_ws;
  float* out = (float*)d_out;

  k_pre1<<<256, 256, 0, stream>>>(eWhhF, eWhhB, eWihF, eWihB, wsb);
  k_enc<<<256, 512, 0, stream>>>(ebF, ebB, C_idx, wsb);
  k_h0<<<256, 512, 0, stream>>>(Wh, Wc, wsb);
  k_pre2p<<<256, 256, 0, stream>>>(dWih, dWhh, Wattn, Wout, Wvoc, wsb);
  k_dec<<<128, 512, 0, stream>>>(C_idx, E_idx, C_pad, db, pgc, pgi, pgh, pgcc, pgb, wsb, out);
}